// Round 8
// baseline (152.187 us; speedup 1.0000x reference)
//
#include <hip/hip_runtime.h>
#include <hip/hip_bf16.h>

// KoopmanOperators: B=16, N=64, T=8, sd=8, h=128, es=128, ud=32, rd=64, gd=32
// BT = 128, NODES = 8192, PAIRS = 524288
//
// Factorizations (exact affine algebra):
//   h_rel   = relu(P_i - P_j + reb1),            P = s @ reW1
//   pre_rel = enc_rel @ rpW[256:320] + A_i + B_j + rpb,
//             A = enc_obj @ rpW[0:128], B = enc_obj @ rpW[128:256]
//
// SINGLE mega-kernel: each block (bt, ig) computes node-encoders for ALL 64
// nodes of its bt (P, Bm; ~3x duplicated vs a separate node kernel — node
// MFMA is trivial) plus own-16-row outputs (eo/obsu/A/x), entirely in LDS.
// Then the pair phase (f16 MFMA) and the composed MLP3 (bf16 MFMA) run on
// LDS-resident data. No inter-kernel tensors at all.
//
// MFMA 16x16x32: A-frag lane l holds A[row=l&15][k=(l>>4)*8+e]; B-frag
// B[k][col=l&15]; C/D lane l reg r = D[(l>>4)*4+r][l&15].
// C->A transposes bounce through XOR-swizzled LDS (granule 16B, g' = g^(row&7)).
//
// LAUNCH-BOUNDS (measured r4-r6): 2nd arg is min BLOCKS/CU. VGPR cap =
// 512/(arg*wavesPerBlock/4). (512,2) -> 128, proven spill-free for the pair
// loop's 96 preloaded weight VGPRs. NEVER raise it above 2 here.

typedef __bf16 bf16x8 __attribute__((ext_vector_type(8)));
typedef _Float16 half8 __attribute__((ext_vector_type(8)));
typedef _Float16 half4 __attribute__((ext_vector_type(4)));
typedef float f32x4 __attribute__((ext_vector_type(4)));

static __device__ __forceinline__ half8 relu8(half8 x) {
    half8 z = {};
    return __builtin_elementwise_max(x, z);
}

// ---------------------------------------------------------------- k_prep
__global__ __launch_bounds__(256) void k_prep(
    const float* __restrict__ sW1, const float* __restrict__ uW1,
    const float* __restrict__ reW1, const float* __restrict__ sW2,
    const float* __restrict__ uW2, const float* __restrict__ upW,
    const float* __restrict__ reW2, const float* __restrict__ rpW,
    const float* __restrict__ cW1, const float* __restrict__ cW2,
    const float* __restrict__ cW3,
    __bf16* __restrict__ Wl1f, __bf16* __restrict__ Ws2f,
    __bf16* __restrict__ Wu2f, __bf16* __restrict__ Wupf,
    __bf16* __restrict__ Wabf, _Float16* __restrict__ W2f,
    _Float16* __restrict__ Wbf, __bf16* __restrict__ Wc1f,
    __bf16* __restrict__ Wc2f, __bf16* __restrict__ Wc3f)
{
    const int tid  = blockIdx.x * 256 + threadIdx.x;
    const int nthr = gridDim.x * 256;

#define PACK(dst, CAST, NKT, NCT, EXPR)                             \
    for (int q = tid; q < (NKT) * (NCT) * 512; q += nthr) {         \
        const int f = q >> 9, rem = q & 511;                        \
        const int lane = rem >> 3, e = rem & 7;                     \
        const int kt = f / (NCT), ct = f % (NCT);                   \
        const int k = kt * 32 + (lane >> 4) * 8 + e;                \
        const int c = ct * 16 + (lane & 15);                        \
        (dst)[q] = (CAST)(EXPR);                                    \
        (void)k; (void)c;                                           \
    }

    PACK(Wl1f, __bf16, 1, 24, (k >= 8 ? 0.f :
        (c < 128 ? sW1[k * 128 + c] :
         c < 256 ? uW1[k * 128 + (c - 128)] : reW1[k * 128 + (c - 256)])))
    PACK(Ws2f, __bf16, 4, 8, sW2[k * 128 + c])
    PACK(Wu2f, __bf16, 4, 2, uW2[k * 32 + c])
    PACK(Wupf, __bf16, 5, 2, (k < 160 ? upW[k * 32 + c] : 0.f))
    PACK(Wabf, __bf16, 4, 8, (c < 64 ? rpW[k * 64 + c] : rpW[(128 + k) * 64 + (c - 64)]))
    PACK(W2f,  _Float16, 4, 4, reW2[k * 64 + c])
    PACK(Wbf,  _Float16, 2, 4, rpW[(256 + k) * 64 + c])
    PACK(Wc1f, __bf16, 7, 8, cW1[k * 128 + c])
    PACK(Wc2f, __bf16, 4, 8, cW2[k * 128 + c])
    PACK(Wc3f, __bf16, 4, 2, cW3[k * 32 + c])
#undef PACK
}

// ---------------------------------------------------------------- k_mega
// 512 blocks = (bt, ig of 4) x 512 thr (8 waves).
__global__ __launch_bounds__(512, 2) void k_mega(
    const float* __restrict__ states,
    const float* __restrict__ sb1, const float* __restrict__ sb2,
    const float* __restrict__ ub1, const float* __restrict__ ub2,
    const float* __restrict__ upb, const float* __restrict__ reb1,
    const float* __restrict__ reb2, const float* __restrict__ rpb,
    const float* __restrict__ cb1, const float* __restrict__ cb2,
    const float* __restrict__ cb3,
    const __bf16* __restrict__ Wl1f, const __bf16* __restrict__ Ws2f,
    const __bf16* __restrict__ Wu2f, const __bf16* __restrict__ Wupf,
    const __bf16* __restrict__ Wabf,
    const _Float16* __restrict__ W2f, const _Float16* __restrict__ Wbf,
    const __bf16* __restrict__ Wc1f, const __bf16* __restrict__ Wc2f,
    const __bf16* __restrict__ Wc3f,
    float* __restrict__ out)
{
    const int t    = threadIdx.x;
    const int lane = t & 63;
    const int w    = t >> 6;             // 0..7
    const int lr   = lane >> 4;
    const int lc   = lane & 15;
    // XCD-aware remap: 4 consecutive logical blocks (same bt) share an XCD L2
    const int bid  = (blockIdx.x & 7) * 64 + (blockIdx.x >> 3);
    const int bt   = bid >> 2;
    const int ig   = bid & 3;
    const int b    = bt >> 3, tstep = bt & 7;
    const int rowb = bt * 64 + ig * 16;  // this block's 16 output rows

    __shared__ _Float16 s_pj[64 * 128];   // 16 KB  P (all 64), swizzled f16
    __shared__ _Float16 s_bmT[64 * 72];   //  9 KB  Bm transposed [c][j]
    __shared__ float    s_ai[16 * 64];    //  4 KB  A_i + rpb (own rows)
    __shared__ __bf16   s_eo[64 * 128];   // 16 KB  eo (all 64); pair: er[8][16*64]
    __shared__ __bf16   s_scr[16 * 256];  //  8 KB  h1|hu scratch; comp h1/h2
    __shared__ __bf16   s_x[16 * 256];    //  8 KB  comp input (own rows)
    __shared__ __bf16   s_eu[16 * 40];    //  1.3 KB eu (own rows, padded)
    __shared__ _Float16 s_rb[128];
    __shared__ float    s_s0[64], s_s4[64];

    if (t < 128) s_rb[t] = (_Float16)reb1[t];
    if (t < 64) {
        const float* sp = &states[((size_t)((b * 64 + t) * 8 + tstep)) * 8];
        s_s0[t] = sp[0];
        s_s4[t] = sp[4];
    }

    // ======================= node phase =======================
    for (int rt = 0; rt < 4; ++rt) {
        // ---- N1: layer 1 for rowtile rt (h1 cts 0-7, P cts 8-15, hu 16-23 own)
        bf16x8 af1 = {};
        if (lr == 0) {
            const int n = rt * 16 + lc;
            const float* sp = &states[((size_t)((b * 64 + n) * 8 + tstep)) * 8];
            const float4 v0 = *reinterpret_cast<const float4*>(sp);
            const float4 v1 = *reinterpret_cast<const float4*>(sp + 4);
            af1[0] = (__bf16)v0.x; af1[1] = (__bf16)v0.y;
            af1[2] = (__bf16)v0.z; af1[3] = (__bf16)v0.w;
            af1[4] = (__bf16)v1.x; af1[5] = (__bf16)v1.y;
            af1[6] = (__bf16)v1.z; af1[7] = (__bf16)v1.w;
        }
        const int nct = (rt == ig) ? 3 : 2;
        for (int ci = 0; ci < nct; ++ci) {
            const int ct = (ci < 2) ? (w * 2 + ci) : (16 + w);
            // Wl1f pack order: 0-7 h1(sW1), 8-15 hu(uW1), 16-23 P(reW1)
            const int wl = (ct < 8) ? ct : (ct < 16 ? ct + 8 : ct - 8);
            const bf16x8 wf = *reinterpret_cast<const bf16x8*>(
                Wl1f + ((size_t)(wl * 64 + lane)) * 8);
            const float bias = (ct < 8) ? sb1[ct * 16 + lc]
                              : (ct >= 16) ? ub1[(ct - 16) * 16 + lc] : 0.f;
            f32x4 acc = {bias, bias, bias, bias};
            acc = __builtin_amdgcn_mfma_f32_16x16x32_bf16(af1, wf, acc, 0, 0, 0);
            #pragma unroll
            for (int r = 0; r < 4; ++r) {
                const int jj = lr * 4 + r;
                if (ct < 8) {
                    const int col = ct * 16 + lc, g = col >> 3;
                    s_scr[jj * 256 + (((g ^ (jj & 7)) << 3) | (col & 7))] =
                        (__bf16)fmaxf(acc[r], 0.f);
                } else if (ct < 16) {
                    const int col = (ct - 8) * 16 + lc, g = col >> 3;
                    const int j64 = rt * 16 + jj;
                    s_pj[j64 * 128 + ((g ^ (j64 & 7)) << 3) + (col & 7)] =
                        (_Float16)acc[r];
                } else {
                    const int col = 128 + (ct - 16) * 16 + lc, g = col >> 3;
                    s_scr[jj * 256 + (((g ^ (jj & 7)) << 3) | (col & 7))] =
                        (__bf16)fmaxf(acc[r], 0.f);
                }
            }
        }
        __syncthreads();

        // ---- N2: eo for rowtile rt (all waves, ct=w); eu if own (waves 0,1)
        {
            const int jr = lc, sw = lc & 7;
            bf16x8 h1f[4];
            #pragma unroll
            for (int kt = 0; kt < 4; ++kt)
                h1f[kt] = *reinterpret_cast<const bf16x8*>(
                    &s_scr[jr * 256 + (((kt * 4 + lr) ^ sw) << 3)]);
            const int ct = w;
            const float bias = sb2[ct * 16 + lc];
            f32x4 acc = {bias, bias, bias, bias};
            #pragma unroll
            for (int kt = 0; kt < 4; ++kt) {
                const bf16x8 wf = *reinterpret_cast<const bf16x8*>(
                    Ws2f + ((size_t)((kt * 8 + ct) * 64 + lane)) * 8);
                acc = __builtin_amdgcn_mfma_f32_16x16x32_bf16(h1f[kt], wf, acc, 0, 0, 0);
            }
            #pragma unroll
            for (int r = 0; r < 4; ++r) {
                const int jj = lr * 4 + r;
                const int j64 = rt * 16 + jj;
                const int col = ct * 16 + lc, g = col >> 3;
                const __bf16 v = (__bf16)fmaxf(acc[r], 0.f);
                s_eo[j64 * 128 + (((g ^ (j64 & 7)) << 3) | (col & 7))] = v;
                if (rt == ig)
                    s_x[jj * 256 + (((g ^ (jj & 7)) << 3) | (col & 7))] = v;
            }
            if (rt == ig && w < 2) {
                bf16x8 huf[4];
                #pragma unroll
                for (int kt = 0; kt < 4; ++kt)
                    huf[kt] = *reinterpret_cast<const bf16x8*>(
                        &s_scr[jr * 256 + (((16 + kt * 4 + lr) ^ sw) << 3)]);
                const float bias2 = ub2[w * 16 + lc];
                f32x4 acc2 = {bias2, bias2, bias2, bias2};
                #pragma unroll
                for (int kt = 0; kt < 4; ++kt) {
                    const bf16x8 wf = *reinterpret_cast<const bf16x8*>(
                        Wu2f + ((size_t)((kt * 2 + w) * 64 + lane)) * 8);
                    acc2 = __builtin_amdgcn_mfma_f32_16x16x32_bf16(huf[kt], wf, acc2, 0, 0, 0);
                }
                #pragma unroll
                for (int r = 0; r < 4; ++r)
                    s_eu[(lr * 4 + r) * 40 + w * 16 + lc] = (__bf16)acc2[r];  // no relu
            }
        }
        __syncthreads();
    }

    // ---- N3: Bm (all 64 rows, 2 tasks/wave); A (waves 0-3); obsu (waves 4,5)
    {
        #pragma unroll
        for (int q = 0; q < 2; ++q) {
            const int task = w * 2 + q;           // 0..15
            const int rt2 = task >> 2;
            const int ct = 4 + (task & 3);        // Wabf ct 4-7 = Bm
            const int j64 = rt2 * 16 + lc, so = j64 & 7;
            bf16x8 eof[4];
            #pragma unroll
            for (int kt = 0; kt < 4; ++kt)
                eof[kt] = *reinterpret_cast<const bf16x8*>(
                    &s_eo[j64 * 128 + (((kt * 4 + lr) ^ so) << 3)]);
            f32x4 acc = {0.f, 0.f, 0.f, 0.f};
            #pragma unroll
            for (int kt = 0; kt < 4; ++kt) {
                const bf16x8 wf = *reinterpret_cast<const bf16x8*>(
                    Wabf + ((size_t)((kt * 8 + ct) * 64 + lane)) * 8);
                acc = __builtin_amdgcn_mfma_f32_16x16x32_bf16(eof[kt], wf, acc, 0, 0, 0);
            }
            #pragma unroll
            for (int r = 0; r < 4; ++r)
                s_bmT[((ct - 4) * 16 + lc) * 72 + rt2 * 16 + lr * 4 + r] =
                    (_Float16)acc[r];
        }
        const int jo = ig * 16 + lc, so2 = jo & 7;
        if (w < 4) {                              // A, ct = w
            bf16x8 eof[4];
            #pragma unroll
            for (int kt = 0; kt < 4; ++kt)
                eof[kt] = *reinterpret_cast<const bf16x8*>(
                    &s_eo[jo * 128 + (((kt * 4 + lr) ^ so2) << 3)]);
            f32x4 acc = {0.f, 0.f, 0.f, 0.f};
            #pragma unroll
            for (int kt = 0; kt < 4; ++kt) {
                const bf16x8 wf = *reinterpret_cast<const bf16x8*>(
                    Wabf + ((size_t)((kt * 8 + w) * 64 + lane)) * 8);
                acc = __builtin_amdgcn_mfma_f32_16x16x32_bf16(eof[kt], wf, acc, 0, 0, 0);
            }
            #pragma unroll
            for (int r = 0; r < 4; ++r) {
                const int col = w * 16 + lc;
                s_ai[(lr * 4 + r) * 64 + col] = acc[r] + rpb[col];
            }
        } else if (w < 6) {                       // obs_u, ct = w-4, K=160
            const int ct = w - 4;
            bf16x8 eof[5];
            #pragma unroll
            for (int kt = 0; kt < 4; ++kt)
                eof[kt] = *reinterpret_cast<const bf16x8*>(
                    &s_eo[jo * 128 + (((kt * 4 + lr) ^ so2) << 3)]);
            eof[4] = *reinterpret_cast<const bf16x8*>(&s_eu[lc * 40 + lr * 8]);
            const float bias = upb[ct * 16 + lc];
            f32x4 acc = {bias, bias, bias, bias};
            #pragma unroll
            for (int kt = 0; kt < 5; ++kt) {
                const bf16x8 wf = *reinterpret_cast<const bf16x8*>(
                    Wupf + ((size_t)((kt * 2 + ct) * 64 + lane)) * 8);
                acc = __builtin_amdgcn_mfma_f32_16x16x32_bf16(eof[kt], wf, acc, 0, 0, 0);
            }
            #pragma unroll
            for (int r = 0; r < 4; ++r) {
                const int jj = lr * 4 + r;
                const int col = 128 + ct * 16 + lc, g = col >> 3;
                s_x[jj * 256 + (((g ^ (jj & 7)) << 3) | (col & 7))] =
                    (__bf16)fmaxf(acc[r], 0.f);
            }
        }
    }
    __syncthreads();

    // ======================= pair phase =======================
    half8 w2f[4][4];
    #pragma unroll
    for (int kt = 0; kt < 4; ++kt)
        #pragma unroll
        for (int ct = 0; ct < 4; ++ct)
            w2f[kt][ct] = *reinterpret_cast<const half8*>(
                W2f + ((size_t)((kt * 4 + ct) * 64 + lane)) * 8);
    half8 wbf[2][4];
    #pragma unroll
    for (int kt = 0; kt < 2; ++kt)
        #pragma unroll
        for (int ct = 0; ct < 4; ++ct)
            wbf[kt][ct] = *reinterpret_cast<const half8*>(
                Wbf + ((size_t)((kt * 4 + ct) * 64 + lane)) * 8);
    float reb2c[4];
    #pragma unroll
    for (int ct = 0; ct < 4; ++ct) reb2c[ct] = reb2[ct * 16 + lc];

    _Float16* er = reinterpret_cast<_Float16*>(s_eo) + w * (16 * 64);
    float rag2[2][4];

    for (int q = 0; q < 2; ++q) {
        const int il = w * 2 + q;
        const int i  = ig * 16 + il;
        const int isw = i & 7;

        half8 pib[4];
        #pragma unroll
        for (int kt = 0; kt < 4; ++kt) {
            const int g = kt * 4 + lr;
            const half8 pv = *reinterpret_cast<const half8*>(
                &s_pj[i * 128 + ((g ^ isw) << 3)]);
            const half8 rb = *reinterpret_cast<const half8*>(&s_rb[g * 8]);
            pib[kt] = pv + rb;
        }
        float aic[4];
        #pragma unroll
        for (int ct = 0; ct < 4; ++ct) aic[ct] = s_ai[il * 64 + ct * 16 + lc];
        const unsigned long long selm = __ballot(
            fabsf(s_s0[i] - s_s0[lane]) > 0.1f ||
            fabsf(s_s4[i] - s_s4[lane]) > 0.1f);

        float ragg[4] = {0.f, 0.f, 0.f, 0.f};

        for (int jt = 0; jt < 4; ++jt) {
            const int j = jt * 16 + lc;
            const int jsw = j & 7;
            half8 af[4];
            #pragma unroll
            for (int kt = 0; kt < 4; ++kt) {
                const int g = (kt * 4 + lr) ^ jsw;
                const half8 pj = *reinterpret_cast<const half8*>(
                    &s_pj[j * 128 + (g << 3)]);
                af[kt] = relu8(pib[kt] - pj);
            }
            // GEMM1: er = relu(h @ reW2 + reb2)
            #pragma unroll
            for (int ct = 0; ct < 4; ++ct) {
                f32x4 acc = {reb2c[ct], reb2c[ct], reb2c[ct], reb2c[ct]};
                #pragma unroll
                for (int kt = 0; kt < 4; ++kt)
                    acc = __builtin_amdgcn_mfma_f32_16x16x32_f16(
                        af[kt], w2f[kt][ct], acc, 0, 0, 0);
                #pragma unroll
                for (int r = 0; r < 4; ++r) {
                    const int jj2 = lr * 4 + r;
                    const int c = ct * 16 + lc;
                    er[jj2 * 64 + ((((c >> 3) ^ (jj2 & 7)) << 3) | (c & 7))] =
                        (_Float16)fmaxf(acc[r], 0.f);
                }
            }
            // GEMM2 + epilogue (B_j folded into acc init via transposed s_bmT)
            half8 a2[2];
            #pragma unroll
            for (int kt = 0; kt < 2; ++kt) {
                const int g = (kt * 4 + lr) ^ (lc & 7);
                a2[kt] = *reinterpret_cast<const half8*>(&er[lc * 64 + (g << 3)]);
            }
            #pragma unroll
            for (int ct = 0; ct < 4; ++ct) {
                const half4 bm4 = *reinterpret_cast<const half4*>(
                    &s_bmT[(ct * 16 + lc) * 72 + jt * 16 + lr * 4]);
                f32x4 acc = {aic[ct] + (float)bm4[0], aic[ct] + (float)bm4[1],
                             aic[ct] + (float)bm4[2], aic[ct] + (float)bm4[3]};
                #pragma unroll
                for (int kt = 0; kt < 2; ++kt)
                    acc = __builtin_amdgcn_mfma_f32_16x16x32_f16(
                        a2[kt], wbf[kt][ct], acc, 0, 0, 0);
                #pragma unroll
                for (int r = 0; r < 4; ++r) {
                    const int jj = jt * 16 + lr * 4 + r;
                    float v = fmaxf(acc[r], 0.f);
                    v = ((selm >> jj) & 1ull) ? v : 0.f;
                    ragg[ct] += v;
                }
            }
        }
        #pragma unroll
        for (int ct = 0; ct < 4; ++ct) {
            ragg[ct] += __shfl_xor(ragg[ct], 16);
            ragg[ct] += __shfl_xor(ragg[ct], 32);
            rag2[q][ct] = ragg[ct];
        }
    }
    // rel_agg into s_x (granules 20..27); rows il are wave-private
    if (lr == 0) {
        #pragma unroll
        for (int q = 0; q < 2; ++q) {
            const int il = w * 2 + q;
            #pragma unroll
            for (int ct = 0; ct < 4; ++ct) {
                const int c = ct * 16 + lc;
                const int gg = 20 + (c >> 3);
                s_x[il * 256 + ((gg ^ (il & 7)) << 3) + (c & 7)] =
                    (__bf16)rag2[q][ct];
            }
        }
    }
    __syncthreads();

    // ======================= comp phase =======================
    __bf16* s_h1 = s_scr;                 // 16*128
    __bf16* s_h2 = s_scr + 16 * 128;      // 16*128

    const int jr = lc;
    const int sw = lc & 7;
    bf16x8 xf[7];
    #pragma unroll
    for (int kt = 0; kt < 7; ++kt)
        xf[kt] = *reinterpret_cast<const bf16x8*>(
            &s_x[jr * 256 + (((kt * 4 + lr) ^ sw) << 3)]);
    {
        const int ct = w;
        const float bias = cb1[ct * 16 + lc];
        f32x4 acc = {bias, bias, bias, bias};
        #pragma unroll
        for (int kt = 0; kt < 7; ++kt) {
            const bf16x8 wf = *reinterpret_cast<const bf16x8*>(
                Wc1f + ((size_t)((kt * 8 + ct) * 64 + lane)) * 8);
            acc = __builtin_amdgcn_mfma_f32_16x16x32_bf16(xf[kt], wf, acc, 0, 0, 0);
        }
        #pragma unroll
        for (int r = 0; r < 4; ++r) {
            const int jj = lr * 4 + r;
            const int col = ct * 16 + lc, g = col >> 3;
            s_h1[jj * 128 + (((g ^ (jj & 7)) << 3) | (col & 7))] =
                (__bf16)fmaxf(acc[r], 0.f);
        }
    }
    __syncthreads();

    {
        bf16x8 hf[4];
        #pragma unroll
        for (int kt = 0; kt < 4; ++kt)
            hf[kt] = *reinterpret_cast<const bf16x8*>(
                &s_h1[jr * 128 + (((kt * 4 + lr) ^ sw) << 3)]);
        const int ct = w;
        const float bias = cb2[ct * 16 + lc];
        f32x4 acc = {bias, bias, bias, bias};
        #pragma unroll
        for (int kt = 0; kt < 4; ++kt) {
            const bf16x8 wf = *reinterpret_cast<const bf16x8*>(
                Wc2f + ((size_t)((kt * 8 + ct) * 64 + lane)) * 8);
            acc = __builtin_amdgcn_mfma_f32_16x16x32_bf16(hf[kt], wf, acc, 0, 0, 0);
        }
        #pragma unroll
        for (int r = 0; r < 4; ++r) {
            const int jj = lr * 4 + r;
            const int col = ct * 16 + lc, g = col >> 3;
            s_h2[jj * 128 + (((g ^ (jj & 7)) << 3) | (col & 7))] =
                (__bf16)fmaxf(acc[r], 0.f);
        }
    }
    __syncthreads();

    if (w < 2) {
        bf16x8 h2f[4];
        #pragma unroll
        for (int kt = 0; kt < 4; ++kt)
            h2f[kt] = *reinterpret_cast<const bf16x8*>(
                &s_h2[jr * 128 + (((kt * 4 + lr) ^ sw) << 3)]);
        const int ct = w;
        const float bias = cb3[ct * 16 + lc];
        f32x4 acc = {bias, bias, bias, bias};
        #pragma unroll
        for (int kt = 0; kt < 4; ++kt) {
            const bf16x8 wf = *reinterpret_cast<const bf16x8*>(
                Wc3f + ((size_t)((kt * 2 + ct) * 64 + lane)) * 8);
            acc = __builtin_amdgcn_mfma_f32_16x16x32_bf16(h2f[kt], wf, acc, 0, 0, 0);
        }
        #pragma unroll
        for (int r = 0; r < 4; ++r) {
            const int rg = rowb + lr * 4 + r;
            out[(size_t)rg * 32 + ct * 16 + lc] = acc[r];
        }
    }
}

// ---------------------------------------------------------------- launch
extern "C" void kernel_launch(void* const* d_in, const int* in_sizes, int n_in,
                              void* d_out, int out_size, void* d_ws, size_t ws_size,
                              hipStream_t stream) {
    const float* states = (const float*)d_in[0];
    const float* sW1  = (const float*)d_in[2];
    const float* sb1  = (const float*)d_in[3];
    const float* sW2  = (const float*)d_in[4];
    const float* sb2  = (const float*)d_in[5];
    const float* uW1  = (const float*)d_in[6];
    const float* ub1  = (const float*)d_in[7];
    const float* uW2  = (const float*)d_in[8];
    const float* ub2  = (const float*)d_in[9];
    const float* upW  = (const float*)d_in[10];
    const float* upb  = (const float*)d_in[11];
    const float* reW1 = (const float*)d_in[12];
    const float* reb1 = (const float*)d_in[13];
    const float* reW2 = (const float*)d_in[14];
    const float* reb2 = (const float*)d_in[15];
    const float* rpW  = (const float*)d_in[16];
    const float* rpb  = (const float*)d_in[17];
    const float* cW1  = (const float*)d_in[18];
    const float* cb1  = (const float*)d_in[19];
    const float* cW2  = (const float*)d_in[20];
    const float* cb2  = (const float*)d_in[21];
    const float* cW3  = (const float*)d_in[22];
    const float* cb3  = (const float*)d_in[23];
    float* out = (float*)d_out;

    // ws: packed weights only
    _Float16* W2f  = (_Float16*)d_ws;                 // 16*512
    _Float16* Wbf  = W2f + 16 * 512;                  // 8*512
    __bf16* Wl1f = (__bf16*)(Wbf + 8 * 512);          // 24*512
    __bf16* Ws2f = Wl1f + 24 * 512;                   // 32*512
    __bf16* Wu2f = Ws2f + 32 * 512;                   // 8*512
    __bf16* Wupf = Wu2f + 8 * 512;                    // 10*512
    __bf16* Wabf = Wupf + 10 * 512;                   // 32*512
    __bf16* Wc1f = Wabf + 32 * 512;                   // 56*512
    __bf16* Wc2f = Wc1f + 56 * 512;                   // 32*512
    __bf16* Wc3f = Wc2f + 32 * 512;                   // 8*512

    k_prep<<<64, 256, 0, stream>>>(sW1, uW1, reW1, sW2, uW2, upW, reW2, rpW,
                                   cW1, cW2, cW3,
                                   Wl1f, Ws2f, Wu2f, Wupf, Wabf, W2f, Wbf,
                                   Wc1f, Wc2f, Wc3f);
    k_mega<<<512, 512, 0, stream>>>(states, sb1, sb2, ub1, ub2, upb,
                                    reb1, reb2, rpb, cb1, cb2, cb3,
                                    Wl1f, Ws2f, Wu2f, Wupf, Wabf, W2f, Wbf,
                                    Wc1f, Wc2f, Wc3f, out);
}

// Round 12
// 146.240 us; speedup vs baseline: 1.0407x; 1.0407x over previous
//
#include <hip/hip_runtime.h>
#include <hip/hip_bf16.h>

// KoopmanOperators: B=16, N=64, T=8, sd=8, h=128, es=128, ud=32, rd=64, gd=32
// BT = 128, NODES = 8192, PAIRS = 524288
//
// Factorizations (exact affine algebra):
//   h_rel   = relu(P_i - P_j + reb1),            P = s @ reW1
//   pre_rel = enc_rel @ rpW[256:320] + A_i + B_j + rpb,
//             A = enc_obj @ rpW[0:128], B = enc_obj @ rpW[128:256]
//
// Single mega-kernel (node + pair + comp per block), manual LDS layout.
// Pair-phase LDS uses PADDED-LINEAR layouts (s_pj stride 136 halves, er
// stride 88) so all hot accesses are base + immediate offset (no per-access
// XOR swizzle ALU); strides chosen 16B-aligned and bank-even.
// Node/comp transposes keep the verified XOR-granule scheme.
//
// LAUNCH-BOUNDS (measured r4-r6): 2nd arg = min BLOCKS/CU; VGPR cap =
// 512/(arg*wavesPerBlock/4). (512,2) -> 128. Never raise above 2 here.
// Wbf lives in LDS during the pair phase (frees 32 VGPRs vs r8).

typedef __bf16 bf16x8 __attribute__((ext_vector_type(8)));
typedef _Float16 half8 __attribute__((ext_vector_type(8)));
typedef _Float16 half4 __attribute__((ext_vector_type(4)));
typedef float f32x4 __attribute__((ext_vector_type(4)));

static __device__ __forceinline__ half8 relu8(half8 x) {
    half8 z = {};
    return __builtin_elementwise_max(x, z);
}

// ---------------------------------------------------------------- k_prep
__global__ __launch_bounds__(256) void k_prep(
    const float* __restrict__ sW1, const float* __restrict__ uW1,
    const float* __restrict__ reW1, const float* __restrict__ sW2,
    const float* __restrict__ uW2, const float* __restrict__ upW,
    const float* __restrict__ reW2, const float* __restrict__ rpW,
    const float* __restrict__ cW1, const float* __restrict__ cW2,
    const float* __restrict__ cW3,
    __bf16* __restrict__ Wl1f, __bf16* __restrict__ Ws2f,
    __bf16* __restrict__ Wu2f, __bf16* __restrict__ Wupf,
    __bf16* __restrict__ Wabf, _Float16* __restrict__ W2f,
    _Float16* __restrict__ Wbf, __bf16* __restrict__ Wc1f,
    __bf16* __restrict__ Wc2f, __bf16* __restrict__ Wc3f)
{
    const int tid  = blockIdx.x * 256 + threadIdx.x;
    const int nthr = gridDim.x * 256;

#define PACK(dst, CAST, NKT, NCT, EXPR)                             \
    for (int q = tid; q < (NKT) * (NCT) * 512; q += nthr) {         \
        const int f = q >> 9, rem = q & 511;                        \
        const int lane = rem >> 3, e = rem & 7;                     \
        const int kt = f / (NCT), ct = f % (NCT);                   \
        const int k = kt * 32 + (lane >> 4) * 8 + e;                \
        const int c = ct * 16 + (lane & 15);                        \
        (dst)[q] = (CAST)(EXPR);                                    \
        (void)k; (void)c;                                           \
    }

    PACK(Wl1f, __bf16, 1, 24, (k >= 8 ? 0.f :
        (c < 128 ? sW1[k * 128 + c] :
         c < 256 ? uW1[k * 128 + (c - 128)] : reW1[k * 128 + (c - 256)])))
    PACK(Ws2f, __bf16, 4, 8, sW2[k * 128 + c])
    PACK(Wu2f, __bf16, 4, 2, uW2[k * 32 + c])
    PACK(Wupf, __bf16, 5, 2, (k < 160 ? upW[k * 32 + c] : 0.f))
    PACK(Wabf, __bf16, 4, 8, (c < 64 ? rpW[k * 64 + c] : rpW[(128 + k) * 64 + (c - 64)]))
    PACK(W2f,  _Float16, 4, 4, reW2[k * 64 + c])
    PACK(Wbf,  _Float16, 2, 4, rpW[(256 + k) * 64 + c])
    PACK(Wc1f, __bf16, 7, 8, cW1[k * 128 + c])
    PACK(Wc2f, __bf16, 4, 8, cW2[k * 128 + c])
    PACK(Wc3f, __bf16, 4, 2, cW3[k * 32 + c])
#undef PACK
}

// ---------------------------------------------------------------- k_mega
// 512 blocks = (bt, ig of 4) x 512 thr (8 waves).
// LDS manual layout (bytes):
constexpr int OFF_PJ   = 0;       // 64*136 half = 17408 (padded-linear P)
constexpr int OFF_BMT  = 17408;   // 64*72 half  = 9216  (Bm transposed [c][j])
constexpr int OFF_AI   = 26624;   // 16*64 f32   = 4096
constexpr int OFF_EO   = 30720;   // 64*128 bf16 = 16384; pair: er (8w*16*88h = 22528 -> 53248)
constexpr int OFF_SCRA = 47104;   // 8192 node scr A; pair: er overflow; comp: h1
constexpr int OFF_SCRB = 55296;   // 8192 node scr B; pair: Wbf copy;   comp: h2
constexpr int OFF_X    = 63488;   // 16*256 bf16 = 8192
constexpr int OFF_EU   = 71680;   // 16*40 bf16 = 1280
constexpr int OFF_RB   = 72960;   // 128 half = 256
constexpr int OFF_S0   = 73216;   // 64 f32 = 256
constexpr int OFF_S4   = 73472;   // 64 f32 = 256
constexpr int LDS_SZ   = 73728;   // 72 KB -> 2 blocks/CU

__global__ __launch_bounds__(512, 2) void k_mega(
    const float* __restrict__ states,
    const float* __restrict__ sb1, const float* __restrict__ sb2,
    const float* __restrict__ ub1, const float* __restrict__ ub2,
    const float* __restrict__ upb, const float* __restrict__ reb1,
    const float* __restrict__ reb2, const float* __restrict__ rpb,
    const float* __restrict__ cb1, const float* __restrict__ cb2,
    const float* __restrict__ cb3,
    const __bf16* __restrict__ Wl1f, const __bf16* __restrict__ Ws2f,
    const __bf16* __restrict__ Wu2f, const __bf16* __restrict__ Wupf,
    const __bf16* __restrict__ Wabf,
    const _Float16* __restrict__ W2f, const _Float16* __restrict__ Wbf,
    const __bf16* __restrict__ Wc1f, const __bf16* __restrict__ Wc2f,
    const __bf16* __restrict__ Wc3f,
    float* __restrict__ out)
{
    __shared__ __align__(16) char lds[LDS_SZ];

    const int t    = threadIdx.x;
    const int lane = t & 63;
    const int w    = t >> 6;             // 0..7
    const int lr   = lane >> 4;
    const int lc   = lane & 15;
    const int bid  = (blockIdx.x & 7) * 64 + (blockIdx.x >> 3);
    const int bt   = bid >> 2;
    const int ig   = bid & 3;
    const int b    = bt >> 3, tstep = bt & 7;
    const int rowb = bt * 64 + ig * 16;

    _Float16* s_pjh = (_Float16*)(lds + OFF_PJ);     // stride 136
    _Float16* s_bmT = (_Float16*)(lds + OFF_BMT);    // stride 72
    float*    s_ai  = (float*)(lds + OFF_AI);
    __bf16*   s_eo  = (__bf16*)(lds + OFF_EO);       // XOR granule, stride 128
    __bf16*   scrA  = (__bf16*)(lds + OFF_SCRA);     // XOR granule, stride 256
    __bf16*   scrB  = (__bf16*)(lds + OFF_SCRB);
    __bf16*   s_x   = (__bf16*)(lds + OFF_X);        // XOR granule, stride 256
    __bf16*   s_eu  = (__bf16*)(lds + OFF_EU);       // stride 40
    _Float16* s_rbh = (_Float16*)(lds + OFF_RB);
    float*    s_s0  = (float*)(lds + OFF_S0);
    float*    s_s4  = (float*)(lds + OFF_S4);

    if (t < 128) s_rbh[t] = (_Float16)reb1[t];
    if (t < 64) {
        const float* sp = &states[((size_t)((b * 64 + t) * 8 + tstep)) * 8];
        s_s0[t] = sp[0];
        s_s4[t] = sp[4];
    }

    // ======================= node phase (scrA/scrB double-buffered) ====
    // layer1 logical ct: 0-7 h1(sW1), 8-15 P(reW1), 16-23 hu(uW1, own rt only)
    auto do_N1 = [&](int rt, __bf16* scr) {
        bf16x8 af1 = {};
        if (lr == 0) {
            const int n = rt * 16 + lc;
            const float* sp = &states[((size_t)((b * 64 + n) * 8 + tstep)) * 8];
            const float4 v0 = *reinterpret_cast<const float4*>(sp);
            const float4 v1 = *reinterpret_cast<const float4*>(sp + 4);
            af1[0] = (__bf16)v0.x; af1[1] = (__bf16)v0.y;
            af1[2] = (__bf16)v0.z; af1[3] = (__bf16)v0.w;
            af1[4] = (__bf16)v1.x; af1[5] = (__bf16)v1.y;
            af1[6] = (__bf16)v1.z; af1[7] = (__bf16)v1.w;
        }
        const int nct = (rt == ig) ? 3 : 2;
        for (int ci = 0; ci < nct; ++ci) {
            const int ct = (ci < 2) ? (w * 2 + ci) : (16 + w);
            const int wl = (ct < 8) ? ct : (ct < 16 ? ct + 8 : ct - 8);
            const bf16x8 wf = *reinterpret_cast<const bf16x8*>(
                Wl1f + ((size_t)(wl * 64 + lane)) * 8);
            const float bias = (ct < 8) ? sb1[ct * 16 + lc]
                              : (ct >= 16) ? ub1[(ct - 16) * 16 + lc] : 0.f;
            f32x4 acc = {bias, bias, bias, bias};
            acc = __builtin_amdgcn_mfma_f32_16x16x32_bf16(af1, wf, acc, 0, 0, 0);
            #pragma unroll
            for (int r = 0; r < 4; ++r) {
                const int jj = lr * 4 + r;
                if (ct < 8) {
                    const int col = ct * 16 + lc, g = col >> 3;
                    scr[jj * 256 + (((g ^ (jj & 7)) << 3) | (col & 7))] =
                        (__bf16)fmaxf(acc[r], 0.f);
                } else if (ct < 16) {
                    s_pjh[(rt * 16 + jj) * 136 + (ct - 8) * 16 + lc] =
                        (_Float16)acc[r];
                } else {
                    const int col = 128 + (ct - 16) * 16 + lc, g = col >> 3;
                    scr[jj * 256 + (((g ^ (jj & 7)) << 3) | (col & 7))] =
                        (__bf16)fmaxf(acc[r], 0.f);
                }
            }
        }
    };
    auto do_N2 = [&](int rt, __bf16* scr) {
        const int jr = lc, sw = lc & 7;
        bf16x8 h1f[4];
        #pragma unroll
        for (int kt = 0; kt < 4; ++kt)
            h1f[kt] = *reinterpret_cast<const bf16x8*>(
                &scr[jr * 256 + (((kt * 4 + lr) ^ sw) << 3)]);
        const int ct = w;
        const float bias = sb2[ct * 16 + lc];
        f32x4 acc = {bias, bias, bias, bias};
        #pragma unroll
        for (int kt = 0; kt < 4; ++kt) {
            const bf16x8 wf = *reinterpret_cast<const bf16x8*>(
                Ws2f + ((size_t)((kt * 8 + ct) * 64 + lane)) * 8);
            acc = __builtin_amdgcn_mfma_f32_16x16x32_bf16(h1f[kt], wf, acc, 0, 0, 0);
        }
        #pragma unroll
        for (int r = 0; r < 4; ++r) {
            const int jj = lr * 4 + r;
            const int j64 = rt * 16 + jj;
            const int col = ct * 16 + lc, g = col >> 3;
            const __bf16 v = (__bf16)fmaxf(acc[r], 0.f);
            s_eo[j64 * 128 + (((g ^ (j64 & 7)) << 3) | (col & 7))] = v;
            if (rt == ig)
                s_x[jj * 256 + (((g ^ (jj & 7)) << 3) | (col & 7))] = v;
        }
        if (rt == ig && w < 2) {
            bf16x8 huf[4];
            #pragma unroll
            for (int kt = 0; kt < 4; ++kt)
                huf[kt] = *reinterpret_cast<const bf16x8*>(
                    &scr[jr * 256 + (((16 + kt * 4 + lr) ^ sw) << 3)]);
            const float bias2 = ub2[w * 16 + lc];
            f32x4 acc2 = {bias2, bias2, bias2, bias2};
            #pragma unroll
            for (int kt = 0; kt < 4; ++kt) {
                const bf16x8 wf = *reinterpret_cast<const bf16x8*>(
                    Wu2f + ((size_t)((kt * 2 + w) * 64 + lane)) * 8);
                acc2 = __builtin_amdgcn_mfma_f32_16x16x32_bf16(huf[kt], wf, acc2, 0, 0, 0);
            }
            #pragma unroll
            for (int r = 0; r < 4; ++r)
                s_eu[(lr * 4 + r) * 40 + w * 16 + lc] = (__bf16)acc2[r];  // no relu
        }
    };

    do_N1(0, scrA);
    __syncthreads();
    for (int rt = 0; rt < 4; ++rt) {
        __bf16* cur = (rt & 1) ? scrB : scrA;
        __bf16* nxt = (rt & 1) ? scrA : scrB;
        do_N2(rt, cur);
        if (rt < 3) do_N1(rt + 1, nxt);
        __syncthreads();
    }

    // ---- N3: Bm all 64 rows (2 tasks/wave); A (waves 0-3); obsu (waves 4,5)
    {
        #pragma unroll
        for (int q = 0; q < 2; ++q) {
            const int task = w * 2 + q;           // 0..15
            const int rt2 = task >> 2;
            const int ct = 4 + (task & 3);        // Wabf ct 4-7 = Bm
            const int j64 = rt2 * 16 + lc, so = j64 & 7;
            bf16x8 eof[4];
            #pragma unroll
            for (int kt = 0; kt < 4; ++kt)
                eof[kt] = *reinterpret_cast<const bf16x8*>(
                    &s_eo[j64 * 128 + (((kt * 4 + lr) ^ so) << 3)]);
            f32x4 acc = {0.f, 0.f, 0.f, 0.f};
            #pragma unroll
            for (int kt = 0; kt < 4; ++kt) {
                const bf16x8 wf = *reinterpret_cast<const bf16x8*>(
                    Wabf + ((size_t)((kt * 8 + ct) * 64 + lane)) * 8);
                acc = __builtin_amdgcn_mfma_f32_16x16x32_bf16(eof[kt], wf, acc, 0, 0, 0);
            }
            #pragma unroll
            for (int r = 0; r < 4; ++r)
                s_bmT[((ct - 4) * 16 + lc) * 72 + rt2 * 16 + lr * 4 + r] =
                    (_Float16)acc[r];
        }
        const int jo = ig * 16 + lc, so2 = jo & 7;
        if (w < 4) {                              // A, ct = w
            bf16x8 eof[4];
            #pragma unroll
            for (int kt = 0; kt < 4; ++kt)
                eof[kt] = *reinterpret_cast<const bf16x8*>(
                    &s_eo[jo * 128 + (((kt * 4 + lr) ^ so2) << 3)]);
            f32x4 acc = {0.f, 0.f, 0.f, 0.f};
            #pragma unroll
            for (int kt = 0; kt < 4; ++kt) {
                const bf16x8 wf = *reinterpret_cast<const bf16x8*>(
                    Wabf + ((size_t)((kt * 8 + w) * 64 + lane)) * 8);
                acc = __builtin_amdgcn_mfma_f32_16x16x32_bf16(eof[kt], wf, acc, 0, 0, 0);
            }
            #pragma unroll
            for (int r = 0; r < 4; ++r) {
                const int col = w * 16 + lc;
                s_ai[(lr * 4 + r) * 64 + col] = acc[r] + rpb[col];
            }
        } else if (w < 6) {                       // obs_u, ct = w-4, K=160
            const int ct = w - 4;
            bf16x8 eof[5];
            #pragma unroll
            for (int kt = 0; kt < 4; ++kt)
                eof[kt] = *reinterpret_cast<const bf16x8*>(
                    &s_eo[jo * 128 + (((kt * 4 + lr) ^ so2) << 3)]);
            eof[4] = *reinterpret_cast<const bf16x8*>(&s_eu[lc * 40 + lr * 8]);
            const float bias = upb[ct * 16 + lc];
            f32x4 acc = {bias, bias, bias, bias};
            #pragma unroll
            for (int kt = 0; kt < 5; ++kt) {
                const bf16x8 wf = *reinterpret_cast<const bf16x8*>(
                    Wupf + ((size_t)((kt * 2 + ct) * 64 + lane)) * 8);
                acc = __builtin_amdgcn_mfma_f32_16x16x32_bf16(eof[kt], wf, acc, 0, 0, 0);
            }
            #pragma unroll
            for (int r = 0; r < 4; ++r) {
                const int jj = lr * 4 + r;
                const int col = 128 + ct * 16 + lc, g = col >> 3;
                s_x[jj * 256 + (((g ^ (jj & 7)) << 3) | (col & 7))] =
                    (__bf16)fmaxf(acc[r], 0.f);
            }
        }
        // stage Wbf into scrB (4096 halves = 512 thr x 8) for the pair phase
        *reinterpret_cast<half8*>((_Float16*)scrB + t * 8) =
            *reinterpret_cast<const half8*>(Wbf + t * 8);
    }
    __syncthreads();

    // ======================= pair phase =======================
    half8 w2f[4][4];
    #pragma unroll
    for (int kt = 0; kt < 4; ++kt)
        #pragma unroll
        for (int ct = 0; ct < 4; ++ct)
            w2f[kt][ct] = *reinterpret_cast<const half8*>(
                W2f + ((size_t)((kt * 4 + ct) * 64 + lane)) * 8);
    float reb2c[4];
    #pragma unroll
    for (int ct = 0; ct < 4; ++ct) reb2c[ct] = reb2[ct * 16 + lc];

    const _Float16* wbl = (const _Float16*)scrB;     // Wbf in LDS
    _Float16* er = (_Float16*)s_eo + w * (16 * 88);  // padded-linear, stride 88
    const int erw = (lr * 4) * 88 + lc;              // write base (elem)
    const int erd = lc * 88 + lr * 8;                // read base (elem)
    float rag2[2][4];

    for (int q = 0; q < 2; ++q) {
        const int il = w * 2 + q;
        const int i  = ig * 16 + il;

        const _Float16* pirow = s_pjh + i * 136;
        half8 pib[4];
        #pragma unroll
        for (int kt = 0; kt < 4; ++kt)
            pib[kt] = *reinterpret_cast<const half8*>(pirow + kt * 32 + lr * 8)
                    + *reinterpret_cast<const half8*>(s_rbh + kt * 32 + lr * 8);
        float aic[4];
        #pragma unroll
        for (int ct = 0; ct < 4; ++ct) aic[ct] = s_ai[il * 64 + ct * 16 + lc];
        const unsigned long long selm = __ballot(
            fabsf(s_s0[i] - s_s0[lane]) > 0.1f ||
            fabsf(s_s4[i] - s_s4[lane]) > 0.1f);

        float ragg[4] = {0.f, 0.f, 0.f, 0.f};

        for (int jt = 0; jt < 4; ++jt) {
            const _Float16* pjr = s_pjh + (jt * 16 + lc) * 136 + lr * 8;
            __builtin_amdgcn_s_setprio(1);
            half8 af[4];
            #pragma unroll
            for (int kt = 0; kt < 4; ++kt)
                af[kt] = relu8(pib[kt] -
                    *reinterpret_cast<const half8*>(pjr + kt * 32));
            // GEMM1: er = relu(h @ reW2 + reb2)
            #pragma unroll
            for (int ct = 0; ct < 4; ++ct) {
                f32x4 acc = {reb2c[ct], reb2c[ct], reb2c[ct], reb2c[ct]};
                #pragma unroll
                for (int kt = 0; kt < 4; ++kt)
                    acc = __builtin_amdgcn_mfma_f32_16x16x32_f16(
                        af[kt], w2f[kt][ct], acc, 0, 0, 0);
                #pragma unroll
                for (int r = 0; r < 4; ++r)
                    er[erw + r * 88 + ct * 16] = (_Float16)fmaxf(acc[r], 0.f);
            }
            // GEMM2 + epilogue (Wbf from LDS; B_j folded into acc init)
            half8 a2[2];
            #pragma unroll
            for (int kt = 0; kt < 2; ++kt)
                a2[kt] = *reinterpret_cast<const half8*>(er + erd + kt * 32);
            #pragma unroll
            for (int ct = 0; ct < 4; ++ct) {
                const half4 bm4 = *reinterpret_cast<const half4*>(
                    s_bmT + (ct * 16 + lc) * 72 + jt * 16 + lr * 4);
                f32x4 acc = {aic[ct] + (float)bm4[0], aic[ct] + (float)bm4[1],
                             aic[ct] + (float)bm4[2], aic[ct] + (float)bm4[3]};
                #pragma unroll
                for (int kt = 0; kt < 2; ++kt) {
                    const half8 wf = *reinterpret_cast<const half8*>(
                        wbl + ((kt * 4 + ct) * 64 + lane) * 8);
                    acc = __builtin_amdgcn_mfma_f32_16x16x32_f16(
                        a2[kt], wf, acc, 0, 0, 0);
                }
                #pragma unroll
                for (int r = 0; r < 4; ++r) {
                    const int jj = jt * 16 + lr * 4 + r;
                    float v = fmaxf(acc[r], 0.f);
                    v = ((selm >> jj) & 1ull) ? v : 0.f;
                    ragg[ct] += v;
                }
            }
            __builtin_amdgcn_s_setprio(0);
        }
        #pragma unroll
        for (int ct = 0; ct < 4; ++ct) {
            ragg[ct] += __shfl_xor(ragg[ct], 16);
            ragg[ct] += __shfl_xor(ragg[ct], 32);
            rag2[q][ct] = ragg[ct];
        }
    }
    // rel_agg into s_x (granules 20..27); rows il are wave-private
    if (lr == 0) {
        #pragma unroll
        for (int q = 0; q < 2; ++q) {
            const int il = w * 2 + q;
            #pragma unroll
            for (int ct = 0; ct < 4; ++ct) {
                const int c = ct * 16 + lc;
                const int gg = 20 + (c >> 3);
                s_x[il * 256 + ((gg ^ (il & 7)) << 3) + (c & 7)] =
                    (__bf16)rag2[q][ct];
            }
        }
    }
    __syncthreads();

    // ======================= comp phase =======================
    __bf16* s_h1 = scrA;
    __bf16* s_h2 = scrB;

    const int jr = lc;
    const int sw = lc & 7;
    bf16x8 xf[7];
    #pragma unroll
    for (int kt = 0; kt < 7; ++kt)
        xf[kt] = *reinterpret_cast<const bf16x8*>(
            &s_x[jr * 256 + (((kt * 4 + lr) ^ sw) << 3)]);
    {
        const int ct = w;
        const float bias = cb1[ct * 16 + lc];
        f32x4 acc = {bias, bias, bias, bias};
        #pragma unroll
        for (int kt = 0; kt < 7; ++kt) {
            const bf16x8 wf = *reinterpret_cast<const bf16x8*>(
                Wc1f + ((size_t)((kt * 8 + ct) * 64 + lane)) * 8);
            acc = __builtin_amdgcn_mfma_f32_16x16x32_bf16(xf[kt], wf, acc, 0, 0, 0);
        }
        #pragma unroll
        for (int r = 0; r < 4; ++r) {
            const int jj = lr * 4 + r;
            const int col = ct * 16 + lc, g = col >> 3;
            s_h1[jj * 128 + (((g ^ (jj & 7)) << 3) | (col & 7))] =
                (__bf16)fmaxf(acc[r], 0.f);
        }
    }
    __syncthreads();

    {
        bf16x8 hf[4];
        #pragma unroll
        for (int kt = 0; kt < 4; ++kt)
            hf[kt] = *reinterpret_cast<const bf16x8*>(
                &s_h1[jr * 128 + (((kt * 4 + lr) ^ sw) << 3)]);
        const int ct = w;
        const float bias = cb2[ct * 16 + lc];
        f32x4 acc = {bias, bias, bias, bias};
        #pragma unroll
        for (int kt = 0; kt < 4; ++kt) {
            const bf16x8 wf = *reinterpret_cast<const bf16x8*>(
                Wc2f + ((size_t)((kt * 8 + ct) * 64 + lane)) * 8);
            acc = __builtin_amdgcn_mfma_f32_16x16x32_bf16(hf[kt], wf, acc, 0, 0, 0);
        }
        #pragma unroll
        for (int r = 0; r < 4; ++r) {
            const int jj = lr * 4 + r;
            const int col = ct * 16 + lc, g = col >> 3;
            s_h2[jj * 128 + (((g ^ (jj & 7)) << 3) | (col & 7))] =
                (__bf16)fmaxf(acc[r], 0.f);
        }
    }
    __syncthreads();

    if (w < 2) {
        bf16x8 h2f[4];
        #pragma unroll
        for (int kt = 0; kt < 4; ++kt)
            h2f[kt] = *reinterpret_cast<const bf16x8*>(
                &s_h2[jr * 128 + (((kt * 4 + lr) ^ sw) << 3)]);
        const int ct = w;
        const float bias = cb3[ct * 16 + lc];
        f32x4 acc = {bias, bias, bias, bias};
        #pragma unroll
        for (int kt = 0; kt < 4; ++kt) {
            const bf16x8 wf = *reinterpret_cast<const bf16x8*>(
                Wc3f + ((size_t)((kt * 2 + ct) * 64 + lane)) * 8);
            acc = __builtin_amdgcn_mfma_f32_16x16x32_bf16(h2f[kt], wf, acc, 0, 0, 0);
        }
        #pragma unroll
        for (int r = 0; r < 4; ++r) {
            const int rg = rowb + lr * 4 + r;
            out[(size_t)rg * 32 + ct * 16 + lc] = acc[r];
        }
    }
}

// ---------------------------------------------------------------- launch
extern "C" void kernel_launch(void* const* d_in, const int* in_sizes, int n_in,
                              void* d_out, int out_size, void* d_ws, size_t ws_size,
                              hipStream_t stream) {
    const float* states = (const float*)d_in[0];
    const float* sW1  = (const float*)d_in[2];
    const float* sb1  = (const float*)d_in[3];
    const float* sW2  = (const float*)d_in[4];
    const float* sb2  = (const float*)d_in[5];
    const float* uW1  = (const float*)d_in[6];
    const float* ub1  = (const float*)d_in[7];
    const float* uW2  = (const float*)d_in[8];
    const float* ub2  = (const float*)d_in[9];
    const float* upW  = (const float*)d_in[10];
    const float* upb  = (const float*)d_in[11];
    const float* reW1 = (const float*)d_in[12];
    const float* reb1 = (const float*)d_in[13];
    const float* reW2 = (const float*)d_in[14];
    const float* reb2 = (const float*)d_in[15];
    const float* rpW  = (const float*)d_in[16];
    const float* rpb  = (const float*)d_in[17];
    const float* cW1  = (const float*)d_in[18];
    const float* cb1  = (const float*)d_in[19];
    const float* cW2  = (const float*)d_in[20];
    const float* cb2  = (const float*)d_in[21];
    const float* cW3  = (const float*)d_in[22];
    const float* cb3  = (const float*)d_in[23];
    float* out = (float*)d_out;

    // ws: packed weights only
    _Float16* W2f  = (_Float16*)d_ws;                 // 16*512
    _Float16* Wbf  = W2f + 16 * 512;                  // 8*512
    __bf16* Wl1f = (__bf16*)(Wbf + 8 * 512);          // 24*512
    __bf16* Ws2f = Wl1f + 24 * 512;                   // 32*512
    __bf16* Wu2f = Ws2f + 32 * 512;                   // 8*512
    __bf16* Wupf = Wu2f + 8 * 512;                    // 10*512
    __bf16* Wabf = Wupf + 10 * 512;                   // 32*512
    __bf16* Wc1f = Wabf + 32 * 512;                   // 56*512
    __bf16* Wc2f = Wc1f + 56 * 512;                   // 32*512
    __bf16* Wc3f = Wc2f + 32 * 512;                   // 8*512

    k_prep<<<64, 256, 0, stream>>>(sW1, uW1, reW1, sW2, uW2, upW, reW2, rpW,
                                   cW1, cW2, cW3,
                                   Wl1f, Ws2f, Wu2f, Wupf, Wabf, W2f, Wbf,
                                   Wc1f, Wc2f, Wc3f);
    k_mega<<<512, 512, 0, stream>>>(states, sb1, sb2, ub1, ub2, upb,
                                    reb1, reb2, rpb, cb1, cb2, cb3,
                                    Wl1f, Ws2f, Wu2f, Wupf, Wabf, W2f, Wbf,
                                    Wc1f, Wc2f, Wc3f, out);
}